// Round 17
// baseline (39.446 us; speedup 1.0000x reference)
//
#include <hip/hip_runtime.h>
#include <math.h>

#define BB 2
#define TSS 12
#define NN 5000
#define EE 80000
#define NHEAD 4
#define NOUT 16
#define NEMB 64
#define NCCH 64
#define KW 3
#define NHOR 12
#define NBT (BB*TSS)     // 24
#define NEG 0.2f
#define CAP 64           // per-node bucket capacity
#define NPB 8            // nodes per block (1 wave per node; 512 threads)
#define XTS 32           // padded row stride of xT (floats)

// workspace layout (4-byte units). NOTE: CS..CB is one contiguous 968-float run.
#define OFF_CUR  0       // 5000 ints
#define OFF_CS   5008    // 4 floats
#define OFF_CD   5012    // 4
#define OFF_WCW  5016    // 768  [o*12 + hd*3 + k]
#define OFF_CB   5784    // 192  [o*3 + k]   (ends at 5976)
#define OFF_XT   6000    // 5000*32 floats = 160000
#define OFF_BKT  166000  // 5000*64 ushorts = 80000 ints

#define TRB 157          // transpose blocks (157*32 = 5024 >= 5000)
#define WTB 4            // wtask blocks

__device__ __forceinline__ float lrelu(float v) { return v >= 0.f ? v : NEG * v; }

// fused small-weight precompute (968 tasks) -> global ws
__device__ __forceinline__ void wtask(int tsk, float* __restrict__ wsF,
    const float* __restrict__ Wg, const float* __restrict__ a_src,
    const float* __restrict__ a_dst, const float* __restrict__ bg,
    const float* __restrict__ Wc)
{
    if (tsk < 768) {                       // WcW[o][hd][k]
        int o = tsk / 12, r = tsk % 12, hd = r / 3, k = r % 3;
        float s = 0.f;
#pragma unroll
        for (int d = 0; d < NOUT; ++d)
            s += Wg[hd * NOUT + d] * Wc[(o * NEMB + hd * NOUT + d) * KW + k];
        wsF[OFF_WCW + tsk] = s;
    } else if (tsk < 960) {                // cb[o][k]
        int q = tsk - 768; int o = q / 3, k = q % 3;
        float s = 0.f;
#pragma unroll
        for (int c = 0; c < NEMB; ++c)
            s += bg[c] * Wc[(o * NEMB + c) * KW + k];
        wsF[OFF_CB + q] = s;
    } else if (tsk < 968) {                // cs[0..3], cd[4..7]
        int i = tsk - 960; int h = i & 3;
        const float* av = (i < 4) ? a_src : a_dst;
        float s = 0.f;
#pragma unroll
        for (int d = 0; d < NOUT; ++d) s += Wg[h * NOUT + d] * av[h * NOUT + d];
        wsF[(i < 4 ? OFF_CS : OFF_CD) + h] = s;
    }
}

// D1: zero cursors + coalesced tiled transpose x -> xT (32-node tiles) + weights
__global__ __launch_bounds__(256) void k_pre(
    const float* __restrict__ x, float* __restrict__ wsF, int* __restrict__ cur,
    const float* __restrict__ Wg, const float* __restrict__ a_src,
    const float* __restrict__ a_dst, const float* __restrict__ bg,
    const float* __restrict__ Wc)
{
    int bid = blockIdx.x, tid = threadIdx.x;
    if (bid < TRB) {
        __shared__ float tile[32][NBT + 1];
        int n0 = bid * 32;
        if (tid < 32 && n0 + tid < NN) cur[n0 + tid] = 0;
        // load: 24 rows x 32 cols, coalesced along n (3 elems/thread)
#pragma unroll
        for (int j = 0; j < 3; ++j) {
            int idx = tid + j * 256;             // 0..767
            int row = idx >> 5, col = idx & 31;  // row=bt, col=n-n0
            if (n0 + col < NN) tile[col][row] = x[row * NN + n0 + col];
        }
        __syncthreads();
        // store: xT[n][bt], contiguous in bt
#pragma unroll
        for (int j = 0; j < 3; ++j) {
            int idx = tid + j * 256;             // 0..767
            int nn = idx / NBT, bt = idx % NBT;
            if (nn < 32 && n0 + nn < NN) wsF[OFF_XT + (n0 + nn) * XTS + bt] = tile[nn][bt];
        }
    } else {
        int tsk = (bid - TRB) * 256 + tid;
        wtask(tsk, wsF, Wg, a_src, a_dst, bg, Wc);
    }
}

// D2: bucket scatter, int4-vectorized (4 edges/thread)
__global__ __launch_bounds__(256) void k_scat(
    const int* __restrict__ ei, int* __restrict__ cur,
    unsigned short* __restrict__ bkt)
{
    int i = blockIdx.x * 256 + threadIdx.x;     // vec-of-4 index, < 20000
    if (i < EE / 4) {
        int4 s4 = ((const int4*)ei)[i];
        int4 d4 = ((const int4*)(ei + EE))[i];
        int sv[4] = { s4.x, s4.y, s4.z, s4.w };
        int dv[4] = { d4.x, d4.y, d4.z, d4.w };
#pragma unroll
        for (int j = 0; j < 4; ++j) {
            int pos = atomicAdd(&cur[dv[j]], 1);
            if ((unsigned)pos < CAP) bkt[dv[j] * CAP + pos] = (unsigned short)sv[j];
        }
    }
}

// D3: seg-softmax-aggregate (shift-invariant, no max) + conv + head linear.
// 8 nodes/block (512 thr): halves per-block weight-stage traffic vs NPB=4.
__global__ __launch_bounds__(512) void k_segfinal(
    const int* __restrict__ cur, const unsigned short* __restrict__ bkt,
    const float* __restrict__ wsF,
    const float* __restrict__ bc, const float* __restrict__ Wh,
    const float* __restrict__ bh, float* __restrict__ out)
{
    int tid = threadIdx.x;
    int u = tid >> 6, ul = tid & 63, g = ul >> 3, gl = ul & 7;
    int node = blockIdx.x * NPB + u;
    int bt0 = 3 * g;

    __shared__ float wS[968];            // cs[4] cd[4] WcW[768] cb[192]
    __shared__ float whS[NHOR * 65];     // Wh padded stride 65
    __shared__ float bcS[NCCH];
    __shared__ float bhS[NHOR];
    __shared__ float sS[NPB][NBT][NHEAD];
    __shared__ float sz[NPB][BB][NCCH];

    // ---- coalesced LDS stage of all small tables ----
    for (int i = tid; i < 968; i += 512) wS[i] = wsF[OFF_CS + i];
    if (tid < 192) {
        int o = tid / 16, c16 = tid % 16;
#pragma unroll
        for (int j = 0; j < 4; ++j)
            whS[o * 65 + c16 * 4 + j] = Wh[o * NCCH + c16 * 4 + j];
    }
    if (tid < NCCH) bcS[tid] = bc[tid];
    if (tid < NHOR) bhS[tid] = bh[tid];

    const float* xT = wsF + OFF_XT;

    // independent loads: count + bucket row (uint4 per lane)
    int cnt = cur[node];
    uint4 raw = ((const uint4*)(bkt + node * CAP))[gl];
    if (cnt > CAP) cnt = CAP;

    int idxr[8];
    idxr[0] = raw.x & 0xFFFF;  idxr[1] = raw.x >> 16;
    idxr[2] = raw.y & 0xFFFF;  idxr[3] = raw.y >> 16;
    idxr[4] = raw.z & 0xFFFF;  idxr[5] = raw.z >> 16;
    idxr[6] = raw.w & 0xFFFF;  idxr[7] = raw.w >> 16;

    int slot0 = gl * 8;
    float msk[8];
#pragma unroll
    for (int i = 0; i < 8; ++i) msk[i] = (slot0 + i < cnt) ? 1.f : 0.f;

    // gather 3 bt x-values per slot (12 contiguous bytes), all issued up-front
    float xsr[3][8];
#pragma unroll
    for (int i = 0; i < 8; ++i) {
        const float* r = xT + idxr[i] * XTS + bt0;
        xsr[0][i] = r[0]; xsr[1][i] = r[1]; xsr[2][i] = r[2];
    }
    float xdt[3];
    {
        const float* r = xT + node * XTS + bt0;
        xdt[0] = r[0]; xdt[1] = r[1]; xdt[2] = r[2];
    }

    __syncthreads();   // wS staged (also orders sS use below)

    float cc[4], qq[4];
#pragma unroll
    for (int h = 0; h < 4; ++h) { cc[h] = wS[h]; qq[h] = wS[4 + h]; }

#pragma unroll
    for (int t = 0; t < 3; ++t) {
#pragma unroll
        for (int h = 0; h < 4; ++h) {
            float dh = qq[h] * xdt[t];
            float a = 0.f, b = 0.f;
#pragma unroll
            for (int i = 0; i < 8; ++i) {
                float xs = xsr[t][i];
                float w = __expf(lrelu(cc[h] * xs + dh)) * msk[i];
                a += w; b += w * xs;
            }
            a += __shfl_xor(a, 1); a += __shfl_xor(a, 2); a += __shfl_xor(a, 4);
            b += __shfl_xor(b, 1); b += __shfl_xor(b, 2); b += __shfl_xor(b, 4);
            if (gl == 0) sS[u][bt0 + t][h] = b / (a + 1e-16f);
        }
    }
    __syncthreads();

    // ---- temporal conv + relu + mean, per output channel o = ul (LDS weights) ----
    int o = ul;
    float wcw[NHEAD][KW];
#pragma unroll
    for (int hd = 0; hd < NHEAD; ++hd)
#pragma unroll
        for (int k = 0; k < KW; ++k)
            wcw[hd][k] = wS[8 + o * (NHEAD * KW) + hd * KW + k];
    float cbk[KW];
#pragma unroll
    for (int k = 0; k < KW; ++k) cbk[k] = wS[776 + o * KW + k];
    float bco = bcS[o];
#pragma unroll
    for (int b = 0; b < BB; ++b) {
        float acc = 0.f;
#pragma unroll
        for (int t = 0; t < TSS; ++t) {
            float zt = bco;
#pragma unroll
            for (int k = 0; k < KW; ++k) {
                int tau = t + k - 1;
                if (tau >= 0 && tau < TSS) {
                    zt += cbk[k];
#pragma unroll
                    for (int hd = 0; hd < NHEAD; ++hd)
                        zt += sS[u][b * TSS + tau][hd] * wcw[hd][k];
                }
            }
            acc += fmaxf(zt, 0.f);
        }
        sz[u][b][o] = acc * (1.f / 12.f);
    }
    __syncthreads();

    if (o < NHOR) {
#pragma unroll
        for (int b = 0; b < BB; ++b) {
            float y = bhS[o];
#pragma unroll
            for (int c = 0; c < NCCH; ++c) y += sz[u][b][c] * whS[o * 65 + c];
            out[(b * NHOR + o) * NN + node] = y;
        }
    }
}

extern "C" void kernel_launch(void* const* d_in, const int* in_sizes, int n_in,
                              void* d_out, int out_size, void* d_ws, size_t ws_size,
                              hipStream_t stream) {
    const float* x     = (const float*)d_in[0];
    const int*   ei    = (const int*)d_in[1];
    const float* Wg    = (const float*)d_in[2];
    const float* a_src = (const float*)d_in[3];
    const float* a_dst = (const float*)d_in[4];
    const float* bg    = (const float*)d_in[5];
    const float* Wc    = (const float*)d_in[6];
    const float* bc    = (const float*)d_in[7];
    const float* Wh    = (const float*)d_in[8];
    const float* bh    = (const float*)d_in[9];
    float* out = (float*)d_out;
    int*   wsI = (int*)d_ws;
    float* wsF = (float*)d_ws;
    unsigned short* bkt = (unsigned short*)(wsI + OFF_BKT);

    hipLaunchKernelGGL(k_pre, dim3(TRB + WTB), dim3(256), 0, stream,
                       x, wsF, wsI + OFF_CUR, Wg, a_src, a_dst, bg, Wc);
    hipLaunchKernelGGL(k_scat, dim3(79), dim3(256), 0, stream,
                       ei, wsI + OFF_CUR, bkt);
    hipLaunchKernelGGL(k_segfinal, dim3(NN / NPB), dim3(512), 0, stream,
                       wsI + OFF_CUR, bkt, wsF, bc, Wh, bh, out);
}

// Round 18
// 37.208 us; speedup vs baseline: 1.0602x; 1.0602x over previous
//
#include <hip/hip_runtime.h>
#include <math.h>

#define BB 2
#define TSS 12
#define NN 5000
#define EE 80000
#define NHEAD 4
#define NOUT 16
#define NEMB 64
#define NCCH 64
#define KW 3
#define NHOR 12
#define NBT (BB*TSS)     // 24
#define NEG 0.2f
#define CAP 64           // per-node bucket capacity
#define NPB 4            // nodes per block (1 wave per node)
#define XTS 32           // padded row stride of xT (floats)

// workspace layout (4-byte units). NOTE: CS..CB is one contiguous 968-float run.
#define OFF_CUR  0       // 5000 ints
#define OFF_CS   5008    // 4 floats
#define OFF_CD   5012    // 4
#define OFF_WCW  5016    // 768  [o*12 + hd*3 + k]
#define OFF_CB   5784    // 192  [o*3 + k]   (ends at 5976)
#define OFF_XT   6000    // 5000*32 floats = 160000
#define OFF_BKT  166000  // 5000*64 ushorts = 80000 ints

#define TRB 79           // transpose blocks (79*64 = 5056 >= 5000)
#define WTB 4            // wtask blocks

__device__ __forceinline__ float lrelu(float v) { return v >= 0.f ? v : NEG * v; }

// fused small-weight precompute (968 tasks) -> global ws
__device__ __forceinline__ void wtask(int tsk, float* __restrict__ wsF,
    const float* __restrict__ Wg, const float* __restrict__ a_src,
    const float* __restrict__ a_dst, const float* __restrict__ bg,
    const float* __restrict__ Wc)
{
    if (tsk < 768) {                       // WcW[o][hd][k]
        int o = tsk / 12, r = tsk % 12, hd = r / 3, k = r % 3;
        float s = 0.f;
#pragma unroll
        for (int d = 0; d < NOUT; ++d)
            s += Wg[hd * NOUT + d] * Wc[(o * NEMB + hd * NOUT + d) * KW + k];
        wsF[OFF_WCW + tsk] = s;
    } else if (tsk < 960) {                // cb[o][k]
        int q = tsk - 768; int o = q / 3, k = q % 3;
        float s = 0.f;
#pragma unroll
        for (int c = 0; c < NEMB; ++c)
            s += bg[c] * Wc[(o * NEMB + c) * KW + k];
        wsF[OFF_CB + q] = s;
    } else if (tsk < 968) {                // cs[0..3], cd[4..7]
        int i = tsk - 960; int h = i & 3;
        const float* av = (i < 4) ? a_src : a_dst;
        float s = 0.f;
#pragma unroll
        for (int d = 0; d < NOUT; ++d) s += Wg[h * NOUT + d] * av[h * NOUT + d];
        wsF[(i < 4 ? OFF_CS : OFF_CD) + h] = s;
    }
}

// D1: zero cursors + coalesced tiled transpose x -> xT + fused weights
__global__ __launch_bounds__(256) void k_pre(
    const float* __restrict__ x, float* __restrict__ wsF, int* __restrict__ cur,
    const float* __restrict__ Wg, const float* __restrict__ a_src,
    const float* __restrict__ a_dst, const float* __restrict__ bg,
    const float* __restrict__ Wc)
{
    int bid = blockIdx.x, tid = threadIdx.x;
    if (bid < TRB) {
        __shared__ float tile[64][NBT + 1];
        int n0 = bid * 64;
        if (tid < 64 && n0 + tid < NN) cur[n0 + tid] = 0;
#pragma unroll
        for (int j = 0; j < 6; ++j) {
            int idx = tid + j * 256;             // 0..1535
            int row = idx >> 6, col = idx & 63;  // row=bt, col=n-n0
            if (n0 + col < NN) tile[col][row] = x[row * NN + n0 + col];
        }
        __syncthreads();
#pragma unroll
        for (int j = 0; j < 6; ++j) {
            int idx = tid + j * 256;
            int nn = idx / NBT, bt = idx % NBT;
            if (n0 + nn < NN) wsF[OFF_XT + (n0 + nn) * XTS + bt] = tile[nn][bt];
        }
    } else {
        int tsk = (bid - TRB) * 256 + tid;
        wtask(tsk, wsF, Wg, a_src, a_dst, bg, Wc);
    }
}

// D2: bucket scatter, int4-vectorized (4 edges/thread)
__global__ __launch_bounds__(256) void k_scat(
    const int* __restrict__ ei, int* __restrict__ cur,
    unsigned short* __restrict__ bkt)
{
    int i = blockIdx.x * 256 + threadIdx.x;     // vec-of-4 index, < 20000
    if (i < EE / 4) {
        int4 s4 = ((const int4*)ei)[i];
        int4 d4 = ((const int4*)(ei + EE))[i];
        int sv[4] = { s4.x, s4.y, s4.z, s4.w };
        int dv[4] = { d4.x, d4.y, d4.z, d4.w };
#pragma unroll
        for (int j = 0; j < 4; ++j) {
            int pos = atomicAdd(&cur[dv[j]], 1);
            if ((unsigned)pos < CAP) bkt[dv[j] * CAP + pos] = (unsigned short)sv[j];
        }
    }
}

// D3: seg-softmax-aggregate (shift-invariant, no max) + conv + head linear.
// Round-11 core + LDS-staged weight tables (kills the per-wave L1 weight fan).
__global__ __launch_bounds__(256) void k_segfinal(
    const int* __restrict__ cur, const unsigned short* __restrict__ bkt,
    const float* __restrict__ wsF,
    const float* __restrict__ bc, const float* __restrict__ Wh,
    const float* __restrict__ bh, float* __restrict__ out)
{
    int tid = threadIdx.x;
    int u = tid >> 6, ul = tid & 63, g = ul >> 3, gl = ul & 7;
    int node = blockIdx.x * NPB + u;
    int bt0 = 3 * g;

    __shared__ float wS[968];            // cs[4] cd[4] WcW[768] cb[192]
    __shared__ float whS[NHOR * 65];     // Wh padded stride 65: bank=(o+c)%32
    __shared__ float bcS[NCCH];
    __shared__ float bhS[NHOR];
    __shared__ float sS[NPB][NBT][NHEAD];
    __shared__ float sz[NPB][BB][NCCH];

    // ---- coalesced LDS stage of all small tables (before softmax; hides
    //      under gather latency; one-time per block) ----
    for (int i = tid; i < 968; i += 256) wS[i] = wsF[OFF_CS + i];
    if (tid < 192) {
        int o = tid / 16, c16 = tid % 16;
#pragma unroll
        for (int j = 0; j < 4; ++j)
            whS[o * 65 + c16 * 4 + j] = Wh[o * NCCH + c16 * 4 + j];
    }
    if (tid < NCCH) bcS[tid] = bc[tid];
    if (tid < NHOR) bhS[tid] = bh[tid];

    const float* xT = wsF + OFF_XT;

    // independent loads: count + bucket row (uint4 per lane)
    int cnt = cur[node];
    uint4 raw = ((const uint4*)(bkt + node * CAP))[gl];
    if (cnt > CAP) cnt = CAP;

    int idxr[8];
    idxr[0] = raw.x & 0xFFFF;  idxr[1] = raw.x >> 16;
    idxr[2] = raw.y & 0xFFFF;  idxr[3] = raw.y >> 16;
    idxr[4] = raw.z & 0xFFFF;  idxr[5] = raw.z >> 16;
    idxr[6] = raw.w & 0xFFFF;  idxr[7] = raw.w >> 16;

    int slot0 = gl * 8;
    float msk[8];
#pragma unroll
    for (int i = 0; i < 8; ++i) msk[i] = (slot0 + i < cnt) ? 1.f : 0.f;

    // gather 3 bt x-values per slot (12 contiguous bytes), all issued up-front
    float xsr[3][8];
#pragma unroll
    for (int i = 0; i < 8; ++i) {
        const float* r = xT + idxr[i] * XTS + bt0;
        xsr[0][i] = r[0]; xsr[1][i] = r[1]; xsr[2][i] = r[2];
    }
    float xdt[3];
    {
        const float* r = xT + node * XTS + bt0;
        xdt[0] = r[0]; xdt[1] = r[1]; xdt[2] = r[2];
    }

    __syncthreads();   // wS staged (also orders sS use below)

    float cc[4], qq[4];
#pragma unroll
    for (int h = 0; h < 4; ++h) { cc[h] = wS[h]; qq[h] = wS[4 + h]; }

#pragma unroll
    for (int t = 0; t < 3; ++t) {
#pragma unroll
        for (int h = 0; h < 4; ++h) {
            float dh = qq[h] * xdt[t];
            float a = 0.f, b = 0.f;
#pragma unroll
            for (int i = 0; i < 8; ++i) {
                float xs = xsr[t][i];
                float w = __expf(lrelu(cc[h] * xs + dh)) * msk[i];
                a += w; b += w * xs;
            }
            a += __shfl_xor(a, 1); a += __shfl_xor(a, 2); a += __shfl_xor(a, 4);
            b += __shfl_xor(b, 1); b += __shfl_xor(b, 2); b += __shfl_xor(b, 4);
            if (gl == 0) sS[u][bt0 + t][h] = b / (a + 1e-16f);
        }
    }
    __syncthreads();

    // ---- temporal conv + relu + mean, per output channel o = ul (LDS weights) ----
    int o = ul;
    float wcw[NHEAD][KW];
#pragma unroll
    for (int hd = 0; hd < NHEAD; ++hd)
#pragma unroll
        for (int k = 0; k < KW; ++k)
            wcw[hd][k] = wS[8 + o * (NHEAD * KW) + hd * KW + k];
    float cbk[KW];
#pragma unroll
    for (int k = 0; k < KW; ++k) cbk[k] = wS[776 + o * KW + k];
    float bco = bcS[o];
#pragma unroll
    for (int b = 0; b < BB; ++b) {
        float acc = 0.f;
#pragma unroll
        for (int t = 0; t < TSS; ++t) {
            float zt = bco;
#pragma unroll
            for (int k = 0; k < KW; ++k) {
                int tau = t + k - 1;
                if (tau >= 0 && tau < TSS) {
                    zt += cbk[k];
#pragma unroll
                    for (int hd = 0; hd < NHEAD; ++hd)
                        zt += sS[u][b * TSS + tau][hd] * wcw[hd][k];
                }
            }
            acc += fmaxf(zt, 0.f);
        }
        sz[u][b][o] = acc * (1.f / 12.f);
    }
    __syncthreads();

    if (o < NHOR) {
#pragma unroll
        for (int b = 0; b < BB; ++b) {
            float y = bhS[o];
#pragma unroll
            for (int c = 0; c < NCCH; ++c) y += sz[u][b][c] * whS[o * 65 + c];
            out[(b * NHOR + o) * NN + node] = y;
        }
    }
}

extern "C" void kernel_launch(void* const* d_in, const int* in_sizes, int n_in,
                              void* d_out, int out_size, void* d_ws, size_t ws_size,
                              hipStream_t stream) {
    const float* x     = (const float*)d_in[0];
    const int*   ei    = (const int*)d_in[1];
    const float* Wg    = (const float*)d_in[2];
    const float* a_src = (const float*)d_in[3];
    const float* a_dst = (const float*)d_in[4];
    const float* bg    = (const float*)d_in[5];
    const float* Wc    = (const float*)d_in[6];
    const float* bc    = (const float*)d_in[7];
    const float* Wh    = (const float*)d_in[8];
    const float* bh    = (const float*)d_in[9];
    float* out = (float*)d_out;
    int*   wsI = (int*)d_ws;
    float* wsF = (float*)d_ws;
    unsigned short* bkt = (unsigned short*)(wsI + OFF_BKT);

    hipLaunchKernelGGL(k_pre, dim3(TRB + WTB), dim3(256), 0, stream,
                       x, wsF, wsI + OFF_CUR, Wg, a_src, a_dst, bg, Wc);
    hipLaunchKernelGGL(k_scat, dim3(79), dim3(256), 0, stream,
                       ei, wsI + OFF_CUR, bkt);
    hipLaunchKernelGGL(k_segfinal, dim3(NN / NPB), dim3(256), 0, stream,
                       wsI + OFF_CUR, bkt, wsF, bc, Wh, bh, out);
}